// Round 1
// 78.030 us; speedup vs baseline: 1.0643x; 1.0643x over previous
//
#include <hip/hip_runtime.h>

#define SEQ_LEN 512
#define EMBED_DIM 768
#define WIDTH_EMB 50
#define NUM_LABELS 9
#define N_SPANS 32768
#define WROW (3 * EMBED_DIM + WIDTH_EMB)   // 2354

// ws layout (floats):
// P1[512*9] | P2[512*9] | P3[512*9] | C3[513*9] (exclusive prefix of P3) | WP[17*9]
#define P1_OFF 0
#define P2_OFF (SEQ_LEN * NUM_LABELS)                      // 4608
#define P3_OFF (2 * SEQ_LEN * NUM_LABELS)                  // 9216
#define C3_OFF (3 * SEQ_LEN * NUM_LABELS)                  // 13824
#define WP_OFF (C3_OFF + (SEQ_LEN + 1) * NUM_LABELS)       // 18441

// 512 token-blocks x 9 waves: wave l computes the 3 segment projections
// P{1,2,3}[token][l] = seq[token] . W[l, seg*768 : (seg+1)*768].
// 9x the wave count of the previous version (4617 waves vs 513) so L2
// load latency is hidden; per-wave chain is 3 dots instead of 27.
// Block 512 handles the width-table projection (+bias).
__global__ __launch_bounds__(576) void proj_kernel(
    const float* __restrict__ seq,    // [512*768]
    const float* __restrict__ wtab,   // [17*50]
    const float* __restrict__ W,      // [9*2354]
    const float* __restrict__ b,      // [9]
    float* __restrict__ ws)
{
    const int blk = blockIdx.x;
    const int t   = threadIdx.x;

    if (blk < SEQ_LEN) {
        const int l    = t >> 6;   // wave id == label
        const int lane = t & 63;

        const float2* srow = (const float2*)(seq + blk * EMBED_DIM); // 384 f2
        float2 s2[6];
#pragma unroll
        for (int k = 0; k < 6; ++k) s2[k] = srow[lane + 64 * k];

        const float2* wbase = (const float2*)(W + l * WROW); // 2354*4 stride: 8B-aligned
        float p[3] = {0.f, 0.f, 0.f};
#pragma unroll
        for (int seg = 0; seg < 3; ++seg) {
#pragma unroll
            for (int k = 0; k < 6; ++k) {
                float2 wv = wbase[seg * 384 + lane + 64 * k];
                p[seg] += s2[k].x * wv.x + s2[k].y * wv.y;
            }
        }
        // three independent butterfly reductions (pipelined shfl chains)
#pragma unroll
        for (int seg = 0; seg < 3; ++seg) {
#pragma unroll
            for (int off = 32; off > 0; off >>= 1)
                p[seg] += __shfl_xor(p[seg], off, 64);
        }
        if (lane == 0) {
            ws[P1_OFF + blk * NUM_LABELS + l] = p[0];
            ws[P2_OFF + blk * NUM_LABELS + l] = p[1];
            ws[P3_OFF + blk * NUM_LABELS + l] = p[2];
        }
    } else {
        // WP[w][l] = b[l] + width_table[w] . W[l, 2304:2354]
        for (int idx = t; idx < 17 * NUM_LABELS; idx += 576) {
            int w = idx / NUM_LABELS;
            int l = idx - w * NUM_LABELS;
            const float* wrow = W + l * WROW + 3 * EMBED_DIM;
            const float* trow = wtab + w * WIDTH_EMB;
            float pp = b[l];
#pragma unroll
            for (int j = 0; j < WIDTH_EMB; ++j) pp += trow[j] * wrow[j];
            ws[WP_OFF + idx] = pp;
        }
    }
}

// One block, 9 waves: wave l computes the exclusive prefix sum of P3[:,l]
// into C3[513][9]. Lane holds 8 tokens in registers -> serial prefix of 8,
// then a 6-step shfl_up wave scan of the lane sums. ~0.3 us.
__global__ __launch_bounds__(576) void scan_kernel(float* __restrict__ ws)
{
    const int l    = threadIdx.x >> 6;
    const int lane = threadIdx.x & 63;

    float v[8];
#pragma unroll
    for (int j = 0; j < 8; ++j)
        v[j] = ws[P3_OFF + (lane * 8 + j) * NUM_LABELS + l];
#pragma unroll
    for (int j = 1; j < 8; ++j) v[j] += v[j - 1];   // inclusive within lane

    const float lsum = v[7];
    float sc = lsum;
#pragma unroll
    for (int off = 1; off < 64; off <<= 1) {
        float u = __shfl_up(sc, off, 64);
        if (lane >= off) sc += u;
    }
    const float excl = sc - lsum;                   // sum of lanes < me

    // C3[idx+1] = sum of P3[0..idx]  (C3[0] = 0)
#pragma unroll
    for (int j = 0; j < 8; ++j)
        ws[C3_OFF + (lane * 8 + j + 1) * NUM_LABELS + l] = excl + v[j];
    if (lane == 0) ws[C3_OFF + l] = 0.f;
}

// Thread per (span,label). Ragged mean = (C3[e]-C3[s])/w -- no loop, no LDS.
// All tables (~55 KB) are L2-hot; 4608 waves hide the gather latency.
#define SPB 64
__global__ __launch_bounds__(576) void span_kernel(
    const int* __restrict__ start_idx,
    const int* __restrict__ end_idx,
    const int* __restrict__ widths,
    const float* __restrict__ ws,
    float* __restrict__ out)
{
    const int t  = threadIdx.x;
    const int sp = t / NUM_LABELS;                 // 0..63
    const int l  = t - sp * NUM_LABELS;
    const int n  = blockIdx.x * SPB + sp;

    const int s = start_idx[n];
    const int e = end_idx[n];
    const int w = widths[n];

    const float c = (ws[C3_OFF + e * NUM_LABELS + l]
                   - ws[C3_OFF + s * NUM_LABELS + l]) / (float)w;

    out[blockIdx.x * (SPB * NUM_LABELS) + t] =
          ws[P1_OFF + s * NUM_LABELS + l]
        + ws[P2_OFF + e * NUM_LABELS + l]
        + ws[WP_OFF + w * NUM_LABELS + l]
        + c;
}

extern "C" void kernel_launch(void* const* d_in, const int* in_sizes, int n_in,
                              void* d_out, int out_size, void* d_ws, size_t ws_size,
                              hipStream_t stream) {
    const float* seq  = (const float*)d_in[0];
    const int*   s    = (const int*)d_in[1];
    const int*   e    = (const int*)d_in[2];
    const int*   w    = (const int*)d_in[3];
    const float* wtab = (const float*)d_in[4];
    const float* W    = (const float*)d_in[5];
    const float* b    = (const float*)d_in[6];
    float* out = (float*)d_out;
    float* ws  = (float*)d_ws;

    proj_kernel<<<SEQ_LEN + 1, 576, 0, stream>>>(seq, wtab, W, b, ws);
    scan_kernel<<<1, 576, 0, stream>>>(ws);
    span_kernel<<<N_SPANS / SPB, 576, 0, stream>>>(s, e, w, ws, out);
}

// Round 3
// 77.079 us; speedup vs baseline: 1.0774x; 1.0123x over previous
//
#include <hip/hip_runtime.h>

#define SEQ_LEN 512
#define EMBED_DIM 768
#define WIDTH_EMB 50
#define NUM_LABELS 9
#define N_SPANS 32768
#define WROW (3 * EMBED_DIM + WIDTH_EMB)   // 2354

// ws layout (floats): P1[512*9] | P2[512*9] | P3[512*9] | WP[17*9]
#define P1_OFF 0
#define P2_OFF (SEQ_LEN * NUM_LABELS)
#define P3_OFF (2 * SEQ_LEN * NUM_LABELS)
#define WP_OFF (3 * SEQ_LEN * NUM_LABELS)

#define SPB 64
#define NTHREADS 576

// 512 token-blocks x 9 waves: wave l computes the 3 segment projections
// P{1,2,3}[token][l] = seq[token] . W[l, seg*768 : (seg+1)*768].
// Block 512 handles the width-table projection (+bias).
__global__ __launch_bounds__(NTHREADS) void proj_kernel(
    const float* __restrict__ seq,    // [512*768]
    const float* __restrict__ wtab,   // [17*50]
    const float* __restrict__ W,      // [9*2354]
    const float* __restrict__ b,      // [9]
    float* __restrict__ ws)
{
    const int blk = blockIdx.x;
    const int t   = threadIdx.x;

    if (blk < SEQ_LEN) {
        const int l    = t >> 6;   // wave id == label
        const int lane = t & 63;

        const float2* srow = (const float2*)(seq + blk * EMBED_DIM); // 384 f2
        float2 s2[6];
#pragma unroll
        for (int k = 0; k < 6; ++k) s2[k] = srow[lane + 64 * k];

        const float2* wbase = (const float2*)(W + l * WROW); // stride 2354 even -> 8B-aligned
        float p[3] = {0.f, 0.f, 0.f};
#pragma unroll
        for (int seg = 0; seg < 3; ++seg) {
#pragma unroll
            for (int k = 0; k < 6; ++k) {
                float2 wv = wbase[seg * 384 + lane + 64 * k];
                p[seg] += s2[k].x * wv.x + s2[k].y * wv.y;
            }
        }
#pragma unroll
        for (int seg = 0; seg < 3; ++seg) {
#pragma unroll
            for (int off = 32; off > 0; off >>= 1)
                p[seg] += __shfl_xor(p[seg], off, 64);
        }
        if (lane == 0) {
            ws[P1_OFF + blk * NUM_LABELS + l] = p[0];
            ws[P2_OFF + blk * NUM_LABELS + l] = p[1];
            ws[P3_OFF + blk * NUM_LABELS + l] = p[2];
        }
    } else {
        // WP[w][l] = b[l] + width_table[w] . W[l, 2304:2354]
        for (int idx = t; idx < 17 * NUM_LABELS; idx += NTHREADS) {
            int w = idx / NUM_LABELS;
            int l = idx - w * NUM_LABELS;
            const float* wrow = W + l * WROW + 3 * EMBED_DIM;
            const float* trow = wtab + w * WIDTH_EMB;
            float pp = b[l];
#pragma unroll
            for (int j = 0; j < WIDTH_EMB; ++j) pp += trow[j] * wrow[j];
            ws[WP_OFF + idx] = pp;
        }
    }
}

// 512 blocks x 576 threads. Each block:
//   (a) stages P1/P2/P3/WP into LDS (coalesced; tables are L2-hot, 55 KB),
//   (b) wave l builds the exclusive prefix C3[:,l] of P3[:,l] in-register
//       (8 tokens/lane serial prefix + 6-step shfl_up wave scan) -- redundant
//       per block, ~0.2 us, cheaper than a separate scan launch,
//   (c) thread = (span,label): out = P1[s] + P2[e] + WP[w] + (C3[e]-C3[s])/w.
// LDS 55.9 KB -> 2 blocks/CU, 18 waves/CU.
__global__ __launch_bounds__(NTHREADS) void span_kernel(
    const int* __restrict__ start_idx,
    const int* __restrict__ end_idx,
    const int* __restrict__ widths,
    const float* __restrict__ ws,
    float* __restrict__ out)
{
    __shared__ float sC3[(SEQ_LEN + 1) * NUM_LABELS];  // 18468 B
    __shared__ float sP1[SEQ_LEN * NUM_LABELS];        // 18432 B
    __shared__ float sP2[SEQ_LEN * NUM_LABELS];        // 18432 B
    __shared__ float sWP[17 * NUM_LABELS];             //   612 B

    const int blk  = blockIdx.x;
    const int t    = threadIdx.x;
    const int l    = t >> 6;
    const int lane = t & 63;

    for (int i = t; i < SEQ_LEN * NUM_LABELS; i += NTHREADS) {
        sP1[i] = ws[P1_OFF + i];
        sP2[i] = ws[P2_OFF + i];
        sC3[NUM_LABELS + i] = ws[P3_OFF + i];   // P3[idx] parked at C3[idx+1]
    }
    if (t < 17 * NUM_LABELS) sWP[t] = ws[WP_OFF + t];
    __syncthreads();

    {
        // wave l scans column l; in-place (each slot read+written by same thread)
        float v[8];
#pragma unroll
        for (int j = 0; j < 8; ++j)
            v[j] = sC3[NUM_LABELS + (lane * 8 + j) * NUM_LABELS + l];
#pragma unroll
        for (int j = 1; j < 8; ++j) v[j] += v[j - 1];
        const float lsum = v[7];
        float sc = lsum;
#pragma unroll
        for (int off = 1; off < 64; off <<= 1) {
            float u = __shfl_up(sc, off, 64);
            if (lane >= off) sc += u;
        }
        const float excl = sc - lsum;           // sum of lanes < me
#pragma unroll
        for (int j = 0; j < 8; ++j)
            sC3[(lane * 8 + j + 1) * NUM_LABELS + l] = excl + v[j];
        if (lane == 0) sC3[l] = 0.f;            // C3[0][l] = 0
    }
    __syncthreads();

    {
        const int sp = t / NUM_LABELS;          // 0..63
        const int ll = t - sp * NUM_LABELS;
        const int n  = blk * SPB + sp;
        const int s  = start_idx[n];
        const int e  = end_idx[n];
        const int w  = widths[n];
        out[blk * (SPB * NUM_LABELS) + t] =
              sP1[s * NUM_LABELS + ll]
            + sP2[e * NUM_LABELS + ll]
            + sWP[w * NUM_LABELS + ll]
            + (sC3[e * NUM_LABELS + ll] - sC3[s * NUM_LABELS + ll]) / (float)w;
    }
}

extern "C" void kernel_launch(void* const* d_in, const int* in_sizes, int n_in,
                              void* d_out, int out_size, void* d_ws, size_t ws_size,
                              hipStream_t stream) {
    const float* seq  = (const float*)d_in[0];
    const int*   s    = (const int*)d_in[1];
    const int*   e    = (const int*)d_in[2];
    const int*   w    = (const int*)d_in[3];
    const float* wtab = (const float*)d_in[4];
    const float* W    = (const float*)d_in[5];
    const float* b    = (const float*)d_in[6];
    float* out = (float*)d_out;
    float* ws  = (float*)d_ws;

    proj_kernel<<<SEQ_LEN + 1, NTHREADS, 0, stream>>>(seq, wtab, W, b, ws);
    span_kernel<<<N_SPANS / SPB, NTHREADS, 0, stream>>>(s, e, w, ws, out);
}

// Round 4
// 75.952 us; speedup vs baseline: 1.0934x; 1.0148x over previous
//
#include <hip/hip_runtime.h>

#define SEQ_LEN 512
#define EMBED_DIM 768
#define WIDTH_EMB 50
#define NUM_LABELS 9
#define N_SPANS 32768
#define WROW (3 * EMBED_DIM + WIDTH_EMB)   // 2354

// ws layout (floats): P1[512*9] | P2[512*9] | P3[512*9] | WP[17*9]
#define P1_OFF 0
#define P2_OFF (SEQ_LEN * NUM_LABELS)
#define P3_OFF (2 * SEQ_LEN * NUM_LABELS)
#define WP_OFF (3 * SEQ_LEN * NUM_LABELS)

#define SPB 64
#define NTHREADS 576

// 512 token-blocks x 9 waves: wave l computes the 3 segment projections
// P{1,2,3}[token][l] = seq[token] . W[l, seg*768 : (seg+1)*768].
// Block 512 handles the width-table projection (+bias).
__global__ __launch_bounds__(NTHREADS) void proj_kernel(
    const float* __restrict__ seq,    // [512*768]
    const float* __restrict__ wtab,   // [17*50]
    const float* __restrict__ W,      // [9*2354]
    const float* __restrict__ b,      // [9]
    float* __restrict__ ws)
{
    const int blk = blockIdx.x;
    const int t   = threadIdx.x;

    if (blk < SEQ_LEN) {
        const int l    = t >> 6;   // wave id == label
        const int lane = t & 63;

        const float2* srow = (const float2*)(seq + blk * EMBED_DIM); // 384 f2
        float2 s2[6];
#pragma unroll
        for (int k = 0; k < 6; ++k) s2[k] = srow[lane + 64 * k];

        const float2* wbase = (const float2*)(W + l * WROW); // stride 2354 even -> 8B-aligned
        float p[3] = {0.f, 0.f, 0.f};
#pragma unroll
        for (int seg = 0; seg < 3; ++seg) {
#pragma unroll
            for (int k = 0; k < 6; ++k) {
                float2 wv = wbase[seg * 384 + lane + 64 * k];
                p[seg] += s2[k].x * wv.x + s2[k].y * wv.y;
            }
        }
#pragma unroll
        for (int seg = 0; seg < 3; ++seg) {
#pragma unroll
            for (int off = 32; off > 0; off >>= 1)
                p[seg] += __shfl_xor(p[seg], off, 64);
        }
        if (lane == 0) {
            ws[P1_OFF + blk * NUM_LABELS + l] = p[0];
            ws[P2_OFF + blk * NUM_LABELS + l] = p[1];
            ws[P3_OFF + blk * NUM_LABELS + l] = p[2];
        }
    } else {
        // WP[w][l] = b[l] + width_table[w] . W[l, 2304:2354]
        for (int idx = t; idx < 17 * NUM_LABELS; idx += NTHREADS) {
            int w = idx / NUM_LABELS;
            int l = idx - w * NUM_LABELS;
            const float* wrow = W + l * WROW + 3 * EMBED_DIM;
            const float* trow = wtab + w * WIDTH_EMB;
            float pp = b[l];
#pragma unroll
            for (int j = 0; j < WIDTH_EMB; ++j) pp += trow[j] * wrow[j];
            ws[WP_OFF + idx] = pp;
        }
    }
}

// 512 blocks x 576 threads. Per block:
//   (a) stage ONLY P3 (-> C3 slot) + WP into LDS (19 KB; 3 blocks/CU,
//       27 waves/CU -- vs 2 blocks/CU when P1/P2 were also staged),
//   (b) wave l builds exclusive prefix C3[:,l] in-register (8 tokens/lane
//       serial prefix + 6-step shfl_up wave scan) -- redundant per block,
//       cheaper than a separate scan launch + gap,
//   (c) thread = (span,label): P1[s], P2[e] read direct from L1/L2 (74 KB
//       table set is cache-hot; one 36 B gather each -- staging them cost
//       more than reading them).
__global__ __launch_bounds__(NTHREADS) void span_kernel(
    const int* __restrict__ start_idx,
    const int* __restrict__ end_idx,
    const int* __restrict__ widths,
    const float* __restrict__ ws,
    float* __restrict__ out)
{
    __shared__ float sC3[(SEQ_LEN + 1) * NUM_LABELS];  // 18468 B
    __shared__ float sWP[17 * NUM_LABELS];             //   612 B

    const int blk  = blockIdx.x;
    const int t    = threadIdx.x;
    const int l    = t >> 6;
    const int lane = t & 63;

    for (int i = t; i < SEQ_LEN * NUM_LABELS; i += NTHREADS)
        sC3[NUM_LABELS + i] = ws[P3_OFF + i];   // P3[idx] parked at C3[idx+1]
    if (t < 17 * NUM_LABELS) sWP[t] = ws[WP_OFF + t];
    __syncthreads();

    {
        // wave l scans column l; in-place (each slot read+written by same thread)
        float v[8];
#pragma unroll
        for (int j = 0; j < 8; ++j)
            v[j] = sC3[NUM_LABELS + (lane * 8 + j) * NUM_LABELS + l];
#pragma unroll
        for (int j = 1; j < 8; ++j) v[j] += v[j - 1];
        const float lsum = v[7];
        float sc = lsum;
#pragma unroll
        for (int off = 1; off < 64; off <<= 1) {
            float u = __shfl_up(sc, off, 64);
            if (lane >= off) sc += u;
        }
        const float excl = sc - lsum;           // sum of lanes < me
#pragma unroll
        for (int j = 0; j < 8; ++j)
            sC3[(lane * 8 + j + 1) * NUM_LABELS + l] = excl + v[j];
        if (lane == 0) sC3[l] = 0.f;            // C3[0][l] = 0
    }
    __syncthreads();

    {
        const int sp = t / NUM_LABELS;          // 0..63
        const int ll = t - sp * NUM_LABELS;
        const int n  = blk * SPB + sp;
        const int s  = start_idx[n];
        const int e  = end_idx[n];
        const int w  = widths[n];
        out[blk * (SPB * NUM_LABELS) + t] =
              ws[P1_OFF + s * NUM_LABELS + ll]
            + ws[P2_OFF + e * NUM_LABELS + ll]
            + sWP[w * NUM_LABELS + ll]
            + (sC3[e * NUM_LABELS + ll] - sC3[s * NUM_LABELS + ll]) / (float)w;
    }
}

extern "C" void kernel_launch(void* const* d_in, const int* in_sizes, int n_in,
                              void* d_out, int out_size, void* d_ws, size_t ws_size,
                              hipStream_t stream) {
    const float* seq  = (const float*)d_in[0];
    const int*   s    = (const int*)d_in[1];
    const int*   e    = (const int*)d_in[2];
    const int*   w    = (const int*)d_in[3];
    const float* wtab = (const float*)d_in[4];
    const float* W    = (const float*)d_in[5];
    const float* b    = (const float*)d_in[6];
    float* out = (float*)d_out;
    float* ws  = (float*)d_ws;

    proj_kernel<<<SEQ_LEN + 1, NTHREADS, 0, stream>>>(seq, wtab, W, b, ws);
    span_kernel<<<N_SPANS / SPB, NTHREADS, 0, stream>>>(s, e, w, ws, out);
}